// Round 7
// baseline (268.692 us; speedup 1.0000x reference)
//
#include <hip/hip_runtime.h>

// GCN 2-layer + edge MLP for SimpleModel_59545426592235.
// R7: (a) k_part = direct scatter. The R6 LDS counting-sort (sbuf/bid/scan,
//     73KB LDS -> 2 blocks/CU, 1M bank-conflict cycles) existed only to
//     coalesce flushes; scattered 4B stores are absorbed by L2 (12.8MB/8
//     XCDs ~ 1.6MB per L2). k_hist now persists its per-chunk histogram to
//     a ccnt[chunk][bucket] matrix so k_part skips re-histogramming.
// (b) nodeA/B/C aggregation loops 4x unrolled: batch part-word loads and
//     pi/qi gathers (independent L2 loads) before the LDS atomics, to hide
//     ~200cy gather latency. Fixed-point u64-packed LDS adds as in R6.

#define BLK 256
#define CH 8192            // edges per chunk
#define BSH 7              // 128 nodes per bucket
#define BSZ 128
#define NBMAX 1024         // max buckets (N <= 131072)
#define NBP 1024           // ccnt row stride
#define S1 262144.0f       // 2^18 conv1 scale
#define S2 65536.0f        // 2^16 conv2 scale
#define BIAS 8388608       // 2^23 low-field bias

// ---- per-chunk LDS histogram -> ccnt row (+ global bucket totals)
__global__ void k_hist(const int* __restrict__ col, int* __restrict__ gcount,
                       int* __restrict__ ccnt, int E, int NB) {
    __shared__ int hist[NBMAX];
    int t = threadIdx.x;
    for (int b = t; b < NB; b += BLK) hist[b] = 0;
    __syncthreads();
    int e0 = blockIdx.x * CH;
    int cnt = min(CH, E - e0);
    for (int k = t; k < cnt; k += BLK)
        atomicAdd(&hist[col[e0 + k] >> BSH], 1);
    __syncthreads();
    int* crow = ccnt + (size_t)blockIdx.x * NBP;
    for (int b = t; b < NB; b += BLK) {
        int h = hist[b];
        crow[b] = h;
        if (h) atomicAdd(&gcount[b], h);
    }
}

// ---- exclusive scan of bucket totals -> gbase[NB+1]; gcursor = gbase
__global__ void k_scan(const int* __restrict__ gcount, int* __restrict__ gbase,
                       int* __restrict__ gcursor, int NB) {
    __shared__ int sa[NBMAX], sb[NBMAX];
    int t = threadIdx.x;
    for (int i = t; i < NBMAX; i += BLK) sa[i] = (i < NB) ? gcount[i] : 0;
    __syncthreads();
    int *src = sa, *dst = sb;
    for (int off = 1; off < NBMAX; off <<= 1) {
        for (int i = t; i < NBMAX; i += BLK)
            dst[i] = src[i] + ((i >= off) ? src[i - off] : 0);
        __syncthreads();
        int* tmp = src; src = dst; dst = tmp;
    }
    for (int i = t; i < NB; i += BLK) {
        int ex = src[i] - gcount[i];
        gbase[i] = ex;
        gcursor[i] = ex;
    }
    if (t == 0) gbase[NB] = src[NB - 1];
}

// ---- partition: reserve from ccnt row, then direct scattered stores
__global__ void k_part(const int* __restrict__ row, const int* __restrict__ col,
                       const int* __restrict__ ccnt, int* __restrict__ gcursor,
                       unsigned* __restrict__ part, int E, int NB) {
    __shared__ int gb[NBMAX];   // reserved base, then running cursor
    int t = threadIdx.x;
    int e0 = blockIdx.x * CH;
    int cnt = min(CH, E - e0);
    const int* crow = ccnt + (size_t)blockIdx.x * NBP;
    for (int b = t; b < NB; b += BLK) {
        int h = crow[b];
        gb[b] = h ? atomicAdd(&gcursor[b], h) : 0;
    }
    __syncthreads();
    for (int k = t; k < cnt; k += BLK) {
        int e = e0 + k;
        int c = col[e];
        int b = c >> BSH;
        int off = atomicAdd(&gb[b], 1);
        part[off] = ((unsigned)row[e] << BSH) | (unsigned)(c & (BSZ - 1));
    }
}

// ---- per-bucket degree count -> deg, dinv, pi = x * dinv (fixed point)
__global__ void k_nodeA(const unsigned* __restrict__ part, const int* __restrict__ gbase,
                        const float2* __restrict__ x2, float* __restrict__ dinv,
                        int* __restrict__ degi, int2* __restrict__ pi, int N) {
    __shared__ int cnt[BSZ];
    int t = threadIdx.x;
    if (t < BSZ) cnt[t] = 0;
    __syncthreads();
    int b = blockIdx.x;
    int j0 = gbase[b], j1 = gbase[b + 1];
    int j = j0 + t;
    for (; j + 3 * BLK < j1; j += 4 * BLK) {
        unsigned w0 = part[j], w1 = part[j + BLK];
        unsigned w2 = part[j + 2 * BLK], w3 = part[j + 3 * BLK];
        atomicAdd(&cnt[w0 & (BSZ - 1)], 1);
        atomicAdd(&cnt[w1 & (BSZ - 1)], 1);
        atomicAdd(&cnt[w2 & (BSZ - 1)], 1);
        atomicAdd(&cnt[w3 & (BSZ - 1)], 1);
    }
    for (; j < j1; j += BLK)
        atomicAdd(&cnt[part[j] & (BSZ - 1)], 1);
    __syncthreads();
    if (t < BSZ) {
        int node = (b << BSH) + t;
        if (node < N) {
            int dg = cnt[t];
            degi[node] = dg;
            float d = rsqrtf((float)(dg + 1));   // +1 self loop
            dinv[node] = d;
            float2 xv = x2[node];
            pi[node] = make_int2(__float2int_rn(xv.x * d * S1),
                                 __float2int_rn(xv.y * d * S1));
        }
    }
}

__device__ __forceinline__ unsigned long long pack64(int2 v) {
    return ((unsigned long long)(unsigned)v.x << 32) | (unsigned)(v.y + BIAS);
}

// ---- per-bucket conv1 aggregate (packed u64 LDS) -> h -> U, V, qi
__global__ void k_nodeB(const unsigned* __restrict__ part, const int* __restrict__ gbase,
                        const float* __restrict__ dinv, const int* __restrict__ degi,
                        const int2* __restrict__ pi,
                        const float* __restrict__ W1, const float* __restrict__ b1,
                        const float* __restrict__ W2, const float* __restrict__ We,
                        const float* __restrict__ be,
                        float4* __restrict__ U, float4* __restrict__ V,
                        int2* __restrict__ qi, int N) {
    __shared__ unsigned long long acc[BSZ];
    __shared__ float sW1[32], sb1[16], sW2[32], sWr[64], sWc[64], sbe[4];
    int t = threadIdx.x;
    if (t < BSZ) acc[t] = 0ull;
    if (t < 32) sW1[t] = W1[t];
    else if (t < 64) sW2[t - 32] = W2[t - 32];
    else if (t < 80) sb1[t - 64] = b1[t - 64];
    else if (t < 144) sWr[t - 80] = We[t - 80];          // We rows 0..15
    else if (t < 208) sWc[t - 144] = We[68 + (t - 144)]; // We rows 17..32
    else if (t < 212) sbe[t - 208] = be[t - 208];
    __syncthreads();
    int b = blockIdx.x;
    int j0 = gbase[b], j1 = gbase[b + 1];
    int j = j0 + t;
    for (; j + 3 * BLK < j1; j += 4 * BLK) {
        unsigned w0 = part[j], w1 = part[j + BLK];
        unsigned w2 = part[j + 2 * BLK], w3 = part[j + 3 * BLK];
        int2 p0 = pi[w0 >> BSH], p1 = pi[w1 >> BSH];
        int2 p2 = pi[w2 >> BSH], p3 = pi[w3 >> BSH];
        atomicAdd(&acc[w0 & (BSZ - 1)], pack64(p0));
        atomicAdd(&acc[w1 & (BSZ - 1)], pack64(p1));
        atomicAdd(&acc[w2 & (BSZ - 1)], pack64(p2));
        atomicAdd(&acc[w3 & (BSZ - 1)], pack64(p3));
    }
    for (; j < j1; j += BLK) {
        unsigned w = part[j];
        atomicAdd(&acc[w & (BSZ - 1)], pack64(pi[w >> BSH]));
    }
    __syncthreads();
    if (t < BSZ) {
        int node = (b << BSH) + t;
        if (node < N) {
            unsigned long long a = acc[t];
            int sx = (int)(unsigned)(a >> 32);
            long long sy = (long long)(unsigned)(a & 0xffffffffull)
                         - (long long)degi[node] * BIAS;
            int2 ps = pi[node];  // self loop
            float d = dinv[node];
            float ax = (float)(ps.x + (long long)sx) * (1.0f / S1);
            float ay = (float)(ps.y + sy) * (1.0f / S1);
            float s0 = d * ax, s1 = d * ay;
            float u0 = sbe[0], u1 = sbe[1], u2 = sbe[2], u3 = sbe[3];
            float v0 = 0.f, v1 = 0.f, v2 = 0.f, v3 = 0.f;
            float w0 = 0.f, w1 = 0.f;
            #pragma unroll
            for (int jj = 0; jj < 16; jj++) {
                float hj = fmaf(s0, sW1[jj], fmaf(s1, sW1[16 + jj], sb1[jj]));
                u0 = fmaf(hj, sWr[4 * jj + 0], u0);
                u1 = fmaf(hj, sWr[4 * jj + 1], u1);
                u2 = fmaf(hj, sWr[4 * jj + 2], u2);
                u3 = fmaf(hj, sWr[4 * jj + 3], u3);
                v0 = fmaf(hj, sWc[4 * jj + 0], v0);
                v1 = fmaf(hj, sWc[4 * jj + 1], v1);
                v2 = fmaf(hj, sWc[4 * jj + 2], v2);
                v3 = fmaf(hj, sWc[4 * jj + 3], v3);
                w0 = fmaf(hj, sW2[2 * jj], w0);
                w1 = fmaf(hj, sW2[2 * jj + 1], w1);
            }
            U[node] = make_float4(u0, u1, u2, u3);
            V[node] = make_float4(v0, v1, v2, v3);
            float qx = w0 * d, qy = w1 * d;
            qi[node] = make_int2(__float2int_rn(qx * S2), __float2int_rn(qy * S2));
        }
    }
}

// ---- edge MLP: pure streaming, no atomics
__global__ void k_edge(const int* __restrict__ row, const int* __restrict__ col,
                       const float* __restrict__ ea, const float4* __restrict__ U,
                       const float4* __restrict__ V, const float* __restrict__ We,
                       float4* __restrict__ eout, int E) {
    __shared__ float sW16[4];
    int t = threadIdx.x;
    if (t < 4) sW16[t] = We[64 + t];   // We row 16 (edge_attr weights)
    __syncthreads();
    int e = blockIdx.x * BLK + t;
    if (e < E) {
        float4 u = U[row[e]];
        float4 v = V[col[e]];
        float av = ea[e];
        float a0 = u.x + fmaf(av, sW16[0], v.x);
        float a1 = u.y + fmaf(av, sW16[1], v.y);
        float a2 = u.z + fmaf(av, sW16[2], v.z);
        float a3 = u.w + fmaf(av, sW16[3], v.w);
        a0 = fmaxf(a0, 0.f); a1 = fmaxf(a1, 0.f);
        a2 = fmaxf(a2, 0.f); a3 = fmaxf(a3, 0.f);
        float m = fmaxf(fmaxf(a0, a1), fmaxf(a2, a3));
        float s = expf(a0 - m) + expf(a1 - m) + expf(a2 - m) + expf(a3 - m);
        float l = m + logf(s);
        eout[e] = make_float4(a0 - l, a1 - l, a2 - l, a3 - l);
    }
}

// ---- per-bucket conv2 aggregate (packed u64 LDS) -> node log_softmax
__global__ void k_nodeC(const unsigned* __restrict__ part, const int* __restrict__ gbase,
                        const float* __restrict__ dinv, const int* __restrict__ degi,
                        const int2* __restrict__ qi,
                        const float* __restrict__ b2, float2* __restrict__ outn, int N) {
    __shared__ unsigned long long acc[BSZ];
    int t = threadIdx.x;
    if (t < BSZ) acc[t] = 0ull;
    __syncthreads();
    int b = blockIdx.x;
    int j0 = gbase[b], j1 = gbase[b + 1];
    int j = j0 + t;
    for (; j + 3 * BLK < j1; j += 4 * BLK) {
        unsigned w0 = part[j], w1 = part[j + BLK];
        unsigned w2 = part[j + 2 * BLK], w3 = part[j + 3 * BLK];
        int2 q0 = qi[w0 >> BSH], q1 = qi[w1 >> BSH];
        int2 q2 = qi[w2 >> BSH], q3 = qi[w3 >> BSH];
        atomicAdd(&acc[w0 & (BSZ - 1)], pack64(q0));
        atomicAdd(&acc[w1 & (BSZ - 1)], pack64(q1));
        atomicAdd(&acc[w2 & (BSZ - 1)], pack64(q2));
        atomicAdd(&acc[w3 & (BSZ - 1)], pack64(q3));
    }
    for (; j < j1; j += BLK) {
        unsigned w = part[j];
        atomicAdd(&acc[w & (BSZ - 1)], pack64(qi[w >> BSH]));
    }
    __syncthreads();
    if (t < BSZ) {
        int node = (b << BSH) + t;
        if (node < N) {
            unsigned long long a = acc[t];
            int sx = (int)(unsigned)(a >> 32);
            long long sy = (long long)(unsigned)(a & 0xffffffffull)
                         - (long long)degi[node] * BIAS;
            int2 qs = qi[node];  // self loop
            float d = dinv[node];
            float bx = (float)(qs.x + (long long)sx) * (1.0f / S2);
            float by = (float)(qs.y + sy) * (1.0f / S2);
            float o0 = fmaf(d, bx, b2[0]);
            float o1 = fmaf(d, by, b2[1]);
            float m = fmaxf(o0, o1);
            float l2 = m + logf(expf(o0 - m) + expf(o1 - m));
            outn[node] = make_float2(o0 - l2, o1 - l2);
        }
    }
}

extern "C" void kernel_launch(void* const* d_in, const int* in_sizes, int n_in,
                              void* d_out, int out_size, void* d_ws, size_t ws_size,
                              hipStream_t stream) {
    const float* x  = (const float*)d_in[0];
    const int*   ei = (const int*)d_in[1];
    const float* ea = (const float*)d_in[2];
    const float* W1 = (const float*)d_in[3];
    const float* b1 = (const float*)d_in[4];
    const float* We = (const float*)d_in[5];
    const float* be = (const float*)d_in[6];
    const float* W2 = (const float*)d_in[7];
    const float* b2 = (const float*)d_in[8];

    const int N = in_sizes[0] / 2;       // 100000
    const int E = in_sizes[2];           // 3200000
    const int* row = ei;
    const int* col = ei + E;
    const int NB  = (N + BSZ - 1) >> BSH;   // 782 buckets
    const int NCH = (E + CH - 1) / CH;      // 391 chunks

    float2* out_nodes = (float2*)d_out;                           // [N,2]
    float4* out_edges = (float4*)((float*)d_out + 2 * (size_t)N); // [E,4]

    // ws layout (bytes):
    char* ws = (char*)d_ws;
    int*      gcount  = (int*)     (ws + 0);         // NBMAX*4
    int*      gbase   = (int*)     (ws + 4096);      // (NBMAX+1)*4 (pad)
    int*      gcursor = (int*)     (ws + 12288);     // NBMAX*4
    float*    dinv    = (float*)   (ws + 16384);     // N*4
    int*      degi    = (int*)     (ws + 416384);    // N*4
    int2*     pi      = (int2*)    (ws + 816384);    // N*8
    int2*     qi      = (int2*)    (ws + 1616384);   // N*8
    float4*   U       = (float4*)  (ws + 2416384);   // N*16
    float4*   V       = (float4*)  (ws + 4016384);   // N*16
    unsigned* part    = (unsigned*)(ws + 5616384);   // E*4 = 12.8 MB
    int*      ccnt    = (int*)     (ws + 18416384);  // NCH*NBP*4 = 1.6 MB -> 20.0 MB

    hipMemsetAsync(gcount, 0, NBMAX * sizeof(int), stream);
    k_hist <<<NCH, BLK, 0, stream>>>(col, gcount, ccnt, E, NB);
    k_scan <<<1,   BLK, 0, stream>>>(gcount, gbase, gcursor, NB);
    k_part <<<NCH, BLK, 0, stream>>>(row, col, ccnt, gcursor, part, E, NB);
    k_nodeA<<<NB,  BLK, 0, stream>>>(part, gbase, (const float2*)x, dinv, degi, pi, N);
    k_nodeB<<<NB,  BLK, 0, stream>>>(part, gbase, dinv, degi, pi, W1, b1, W2, We, be, U, V, qi, N);
    k_edge <<<(E + BLK - 1) / BLK, BLK, 0, stream>>>(row, col, ea, U, V, We, out_edges, E);
    k_nodeC<<<NB,  BLK, 0, stream>>>(part, gbase, dinv, degi, qi, b2, out_nodes, N);
}